// Round 5
// baseline (50.398 us; speedup 1.0000x reference)
//
#include <hip/hip_runtime.h>
#include <math.h>

#define NROWS 128
#define KDIM  1024
#define ODIM  512
#define NB    32
#define BS    32

__device__ __forceinline__ int clz32(unsigned x) { return x ? __builtin_clz(x) : 32; }

// Signed-NAF truncation residual: returns the KEPT value of P (product*4096)
// given isum = intra + s, s = 32 - dbase.  drop = NAF_width - d
//                                               = (32 - clz) - (dbase - intra)
//                                               = intra + (32 - dbase) - clz.
__device__ __forceinline__ int naf_keep(int P, int isum) {
  const int h = P >> 1;                       // arithmetic shift: signed NAF
  const int t = P + h;
  const int pos = t & ~h;                     // positive-digit mask (sign-swapped
  const int ng  = h & ~t;                     //  for P<0; pos-ng == P exactly)
  const int lz  = __builtin_clz((unsigned)((pos | ng) | 1));
  int drop = isum - lz;
  drop = drop < 0 ? 0 : (drop > 31 ? 31 : drop);
  const int m = (int)((1u << drop) - 1u);     // low (width-d) NAF digit mask
  return P - ((pos & m) - (ng & m));          // P minus dropped part
}

// ---------------- prep: quantize x rows -> packed (intra<<8 | int8 q), scales, log2(scales)
__global__ void prep_x_kernel(const float* __restrict__ x,
                              unsigned short* __restrict__ xp,
                              float* __restrict__ xs, float* __restrict__ lxs) {
  int tid = blockIdx.x * blockDim.x + threadIdx.x;
  if (tid >= NROWS * NB) return;
  int row = tid >> 5, blk = tid & 31;
  const float4* p = (const float4*)(x + (size_t)row * KDIM + blk * BS);
  float v[32];
  float m = 0.f;
#pragma unroll
  for (int i = 0; i < 8; ++i) {
    float4 f = p[i];
    v[4*i+0] = f.x; v[4*i+1] = f.y; v[4*i+2] = f.z; v[4*i+3] = f.w;
    m = fmaxf(m, fmaxf(fmaxf(fabsf(f.x), fabsf(f.y)), fmaxf(fabsf(f.z), fabsf(f.w))));
  }
  float scale = fmaxf(m / 1.984375f, 1e-30f);
  int q[32], e[32], emax = -60;
#pragma unroll
  for (int i = 0; i < 32; ++i) {
    float t = v[i] / scale * 64.0f;       // IEEE div + exact pow2 mul, matches ref
    int qi = (int)rintf(t);               // round-half-even, matches jnp.round
    q[i] = qi;
    int a = qi < 0 ? -qi : qi;
    int ei = a ? (31 - clz32((unsigned)a)) - 6 : -60;  // floor(log2(|q|/64)) exact
    e[i] = ei;
    emax = ei > emax ? ei : emax;
  }
  unsigned short u[32];
#pragma unroll
  for (int i = 0; i < 32; ++i)
    u[i] = (unsigned short)(((emax - e[i]) << 8) | (q[i] & 0xFF));
  uint4* dst = (uint4*)(xp + (size_t)row * KDIM + blk * BS);
#pragma unroll
  for (int i = 0; i < 4; ++i) {
    uint4 w4;
    w4.x = (unsigned)u[8*i+0] | ((unsigned)u[8*i+1] << 16);
    w4.y = (unsigned)u[8*i+2] | ((unsigned)u[8*i+3] << 16);
    w4.z = (unsigned)u[8*i+4] | ((unsigned)u[8*i+5] << 16);
    w4.w = (unsigned)u[8*i+6] | ((unsigned)u[8*i+7] << 16);
    dst[i] = w4;
  }
  xs[tid] = scale;
  lxs[tid] = (float)log2((double)scale);  // ~correctly-rounded fp32 log2
}

// ---------------- prep: quantize w rows -> int8 q, scales, log2(scales)
__global__ void prep_w_kernel(const float* __restrict__ wgt,
                              unsigned char* __restrict__ wq,
                              float* __restrict__ wsc, float* __restrict__ lws) {
  int tid = blockIdx.x * blockDim.x + threadIdx.x;
  if (tid >= ODIM * NB) return;
  int row = tid >> 5, blk = tid & 31;
  const float4* p = (const float4*)(wgt + (size_t)row * KDIM + blk * BS);
  float v[32];
  float m = 0.f;
#pragma unroll
  for (int i = 0; i < 8; ++i) {
    float4 f = p[i];
    v[4*i+0] = f.x; v[4*i+1] = f.y; v[4*i+2] = f.z; v[4*i+3] = f.w;
    m = fmaxf(m, fmaxf(fmaxf(fabsf(f.x), fabsf(f.y)), fmaxf(fabsf(f.z), fabsf(f.w))));
  }
  float scale = fmaxf(m / 1.984375f, 1e-30f);
  unsigned char c[32];
#pragma unroll
  for (int i = 0; i < 32; ++i) {
    float t = v[i] / scale * 64.0f;
    int qi = (int)rintf(t);
    c[i] = (unsigned char)(qi & 0xFF);
  }
  uint4* dst = (uint4*)(wq + (size_t)row * KDIM + blk * BS);
#pragma unroll
  for (int i = 0; i < 2; ++i) {
    uint4 w4;
    w4.x = (unsigned)c[16*i+ 0] | ((unsigned)c[16*i+ 1] << 8) | ((unsigned)c[16*i+ 2] << 16) | ((unsigned)c[16*i+ 3] << 24);
    w4.y = (unsigned)c[16*i+ 4] | ((unsigned)c[16*i+ 5] << 8) | ((unsigned)c[16*i+ 6] << 16) | ((unsigned)c[16*i+ 7] << 24);
    w4.z = (unsigned)c[16*i+ 8] | ((unsigned)c[16*i+ 9] << 8) | ((unsigned)c[16*i+10] << 16) | ((unsigned)c[16*i+11] << 24);
    w4.w = (unsigned)c[16*i+12] | ((unsigned)c[16*i+13] << 8) | ((unsigned)c[16*i+14] << 16) | ((unsigned)c[16*i+15] << 24);
    dst[i] = w4;
  }
  wsc[tid] = scale;
  lws[tid] = (float)log2((double)scale);
}

// ---------------- main: 16n x 16o tile, 4-way K-split, 1024 threads (16 waves/CU)
__global__ __launch_bounds__(1024, 4)
void msd_main_kernel(const unsigned short* __restrict__ xp,
                     const unsigned char* __restrict__ wq,
                     const float* __restrict__ xs, const float* __restrict__ lxs,
                     const float* __restrict__ wsc, const float* __restrict__ lws,
                     const float* __restrict__ bias, float* __restrict__ out) {
  __shared__ unsigned short sx[16][1032];   // row stride 2064B -> banks 4*tn apart
  __shared__ unsigned char  swq[16][1040];  // 2-way conflict only (free)
  __shared__ float sxs[16][33], slx[16][33], sws[16][33], slw[16][33];
  __shared__ float sred[3 * 256];
  const int tid = threadIdx.x;
  const int n0 = blockIdx.x * 16, o0 = blockIdx.y * 16;

  // stage x tile: 16 rows x 1024 packed ushorts
  for (int i = tid; i < 16 * 128; i += 1024) {
    int r = i >> 7, c = i & 127;
    uint4 d = ((const uint4*)(xp + (size_t)(n0 + r) * KDIM))[c];
    *(uint4*)&sx[r][c * 8] = d;
  }
  // stage w tile: 16 rows x 1024 bytes
  for (int i = tid; i < 16 * 64; i += 1024) {
    int r = i >> 6, c = i & 63;
    uint4 d = ((const uint4*)(wq + (size_t)(o0 + r) * KDIM))[c];
    *(uint4*)&swq[r][c * 16] = d;
  }
  if (tid < 512) {
    int r = tid >> 5, b = tid & 31;
    sxs[r][b] = xs[(n0 + r) * NB + b];
    slx[r][b] = lxs[(n0 + r) * NB + b];
    sws[r][b] = wsc[(o0 + r) * NB + b];
    slw[r][b] = lws[(o0 + r) * NB + b];
  }
  __syncthreads();

  const int kh = tid >> 8, idx = tid & 255, tn = idx >> 4, to = idx & 15;

  // e_max over blocks (combined_e = floor(lx + lw))
  float emf = -1e30f;
#pragma unroll
  for (int b = 0; b < NB; ++b)
    emf = fmaxf(emf, floorf(slx[tn][b] + slw[to][b]));
  const int iemax = (int)emf;
  // s = 32 - dbase = 24 + min(iemax,0) - ice   (dbase = 8+max(emax,0)-emax+ice)
  const int sbase = 24 + (iemax < 0 ? iemax : 0);

  float facc = 0.f;
  const int b0 = kh * 8;
#pragma unroll 1
  for (int bb = 0; bb < 8; ++bb) {
    const int b = b0 + bb;
    const int ice = (int)floorf(slx[tn][b] + slw[to][b]);
    const int s = sbase - ice;
    uint4 xv0 = *(const uint4*)&sx[tn][b * 32 + 0];
    uint4 xv1 = *(const uint4*)&sx[tn][b * 32 + 8];
    uint4 xv2 = *(const uint4*)&sx[tn][b * 32 + 16];
    uint4 xv3 = *(const uint4*)&sx[tn][b * 32 + 24];
    unsigned xd[16] = {xv0.x, xv0.y, xv0.z, xv0.w, xv1.x, xv1.y, xv1.z, xv1.w,
                       xv2.x, xv2.y, xv2.z, xv2.w, xv3.x, xv3.y, xv3.z, xv3.w};
    uint4 wv0 = *(const uint4*)&swq[to][b * 32];
    uint4 wv1 = *(const uint4*)&swq[to][b * 32 + 16];
    unsigned wb[8] = {wv0.x, wv0.y, wv0.z, wv0.w, wv1.x, wv1.y, wv1.z, wv1.w};
    int bacc = 0;
#pragma unroll
    for (int j = 0; j < 16; ++j) {        // 2 elements per x-dword
      const unsigned xw = xd[j];
      const unsigned ww = wb[j >> 1];
      const int ix0 = ((int)(xw << 24)) >> 24;          // bfe_i32
      const int in0 = (int)((xw >> 8) & 0xFFu);         // bfe_u32
      const int ix1 = ((int)(xw << 8)) >> 24;
      const int in1 = (int)(xw >> 24);
      int iw0, iw1;
      if (j & 1) { iw0 = ((int)(ww << 8)) >> 24; iw1 = ((int)ww) >> 24; }
      else       { iw0 = ((int)(ww << 24)) >> 24; iw1 = ((int)(ww << 16)) >> 24; }
      bacc += naf_keep(ix0 * iw0, in0 + s);
      bacc += naf_keep(ix1 * iw1, in1 + s);
    }
    facc += sxs[tn][b] * sws[to][b] * (float)bacc;  // exact: block_dot = bacc/4096
  }

  if (kh) sred[(kh - 1) * 256 + idx] = facc;
  __syncthreads();
  if (!kh) {
    float r = (facc + sred[idx] + sred[256 + idx] + sred[512 + idx])
              * (1.0f / 4096.0f) + bias[o0 + to];
    out[(size_t)(n0 + tn) * ODIM + (o0 + to)] = r;
  }
}

extern "C" void kernel_launch(void* const* d_in, const int* in_sizes, int n_in,
                              void* d_out, int out_size, void* d_ws, size_t ws_size,
                              hipStream_t stream) {
  const float* x    = (const float*)d_in[0];
  const float* wgt  = (const float*)d_in[1];
  const float* bias = (const float*)d_in[2];
  float* out = (float*)d_out;
  char* ws = (char*)d_ws;
  // workspace layout (16B-aligned)
  unsigned short* xp  = (unsigned short*)(ws + 0);       // 128*1024*2 = 262144
  unsigned char*  wq  = (unsigned char*)(ws + 262144);   // 512*1024   = 524288
  float* xs  = (float*)(ws + 786432);                    // 128*32*4   = 16384
  float* lxs = (float*)(ws + 802816);                    // 16384
  float* wsc = (float*)(ws + 819200);                    // 512*32*4   = 65536
  float* lws = (float*)(ws + 884736);                    // 65536 -> total 950272

  hipLaunchKernelGGL(prep_x_kernel, dim3(16), dim3(256), 0, stream, x, xp, xs, lxs);
  hipLaunchKernelGGL(prep_w_kernel, dim3(64), dim3(256), 0, stream, wgt, wq, wsc, lws);
  hipLaunchKernelGGL(msd_main_kernel, dim3(8, 32), dim3(1024), 0, stream,
                     xp, wq, xs, lxs, wsc, lws, bias, out);
}

// Round 7
// 49.950 us; speedup vs baseline: 1.0090x; 1.0090x over previous
//
#include <hip/hip_runtime.h>
#include <math.h>

#define NROWS 128
#define KDIM  1024
#define ODIM  512
#define NB    32
#define BS    32

__device__ __forceinline__ int clz32(unsigned x) { return x ? __builtin_clz(x) : 32; }

// Signed-NAF truncation residual: returns the KEPT value of P (product*4096)
// given isum = intra + s, s = 32 - dbase.  h=P>>1 (arith), t=P+h.
// Canonical signed NAF digit sets: pos=t&~h, ng=h&~t; pos|ng == t^h;
// dropped = (pos&m)-(ng&m) == (t&m)-(h&m)   [carry-free bit partition]
// kept = P - dropped.  m = (1<<drop)-1 built unsigned (no UB).
__device__ __forceinline__ int naf_keep(int P, int isum) {
  const int h = P >> 1;
  const int t = P + h;
  const int lz = __builtin_clz(((unsigned)(t ^ h)) | 1u);
  int drop = isum - lz;
  drop = drop < 0 ? 0 : (drop > 31 ? 31 : drop);   // v_med3_i32
  const int m = (int)((1u << drop) - 1u);
  return P - ((t & m) - (h & m));
}

// ---------------- prep: quantize x rows -> packed (intra<<8 | int8 q), scales, log2(scales)
__global__ void prep_x_kernel(const float* __restrict__ x,
                              unsigned short* __restrict__ xp,
                              float* __restrict__ xs, float* __restrict__ lxs) {
  int tid = blockIdx.x * blockDim.x + threadIdx.x;
  if (tid >= NROWS * NB) return;
  int row = tid >> 5, blk = tid & 31;
  const float4* p = (const float4*)(x + (size_t)row * KDIM + blk * BS);
  float v[32];
  float m = 0.f;
#pragma unroll
  for (int i = 0; i < 8; ++i) {
    float4 f = p[i];
    v[4*i+0] = f.x; v[4*i+1] = f.y; v[4*i+2] = f.z; v[4*i+3] = f.w;
    m = fmaxf(m, fmaxf(fmaxf(fabsf(f.x), fabsf(f.y)), fmaxf(fabsf(f.z), fabsf(f.w))));
  }
  float scale = fmaxf(m / 1.984375f, 1e-30f);
  int q[32], e[32], emax = -60;
#pragma unroll
  for (int i = 0; i < 32; ++i) {
    float t = v[i] / scale * 64.0f;       // IEEE div + exact pow2 mul, matches ref
    int qi = (int)rintf(t);               // round-half-even, matches jnp.round
    q[i] = qi;
    int a = qi < 0 ? -qi : qi;
    int ei = a ? (31 - clz32((unsigned)a)) - 6 : -60;  // floor(log2(|q|/64)) exact
    e[i] = ei;
    emax = ei > emax ? ei : emax;
  }
  unsigned short u[32];
#pragma unroll
  for (int i = 0; i < 32; ++i)
    u[i] = (unsigned short)(((emax - e[i]) << 8) | (q[i] & 0xFF));
  uint4* dst = (uint4*)(xp + (size_t)row * KDIM + blk * BS);
#pragma unroll
  for (int i = 0; i < 4; ++i) {
    uint4 w4;
    w4.x = (unsigned)u[8*i+0] | ((unsigned)u[8*i+1] << 16);
    w4.y = (unsigned)u[8*i+2] | ((unsigned)u[8*i+3] << 16);
    w4.z = (unsigned)u[8*i+4] | ((unsigned)u[8*i+5] << 16);
    w4.w = (unsigned)u[8*i+6] | ((unsigned)u[8*i+7] << 16);
    dst[i] = w4;
  }
  xs[tid] = scale;
  lxs[tid] = (float)log2((double)scale);  // ~correctly-rounded fp32 log2
}

// ---------------- prep: quantize w rows -> int8 q, scales, log2(scales)
__global__ void prep_w_kernel(const float* __restrict__ wgt,
                              unsigned char* __restrict__ wq,
                              float* __restrict__ wsc, float* __restrict__ lws) {
  int tid = blockIdx.x * blockDim.x + threadIdx.x;
  if (tid >= ODIM * NB) return;
  int row = tid >> 5, blk = tid & 31;
  const float4* p = (const float4*)(wgt + (size_t)row * KDIM + blk * BS);
  float v[32];
  float m = 0.f;
#pragma unroll
  for (int i = 0; i < 8; ++i) {
    float4 f = p[i];
    v[4*i+0] = f.x; v[4*i+1] = f.y; v[4*i+2] = f.z; v[4*i+3] = f.w;
    m = fmaxf(m, fmaxf(fmaxf(fabsf(f.x), fabsf(f.y)), fmaxf(fabsf(f.z), fabsf(f.w))));
  }
  float scale = fmaxf(m / 1.984375f, 1e-30f);
  unsigned char c[32];
#pragma unroll
  for (int i = 0; i < 32; ++i) {
    float t = v[i] / scale * 64.0f;
    int qi = (int)rintf(t);
    c[i] = (unsigned char)(qi & 0xFF);
  }
  uint4* dst = (uint4*)(wq + (size_t)row * KDIM + blk * BS);
#pragma unroll
  for (int i = 0; i < 2; ++i) {
    uint4 w4;
    w4.x = (unsigned)c[16*i+ 0] | ((unsigned)c[16*i+ 1] << 8) | ((unsigned)c[16*i+ 2] << 16) | ((unsigned)c[16*i+ 3] << 24);
    w4.y = (unsigned)c[16*i+ 4] | ((unsigned)c[16*i+ 5] << 8) | ((unsigned)c[16*i+ 6] << 16) | ((unsigned)c[16*i+ 7] << 24);
    w4.z = (unsigned)c[16*i+ 8] | ((unsigned)c[16*i+ 9] << 8) | ((unsigned)c[16*i+10] << 16) | ((unsigned)c[16*i+11] << 24);
    w4.w = (unsigned)c[16*i+12] | ((unsigned)c[16*i+13] << 8) | ((unsigned)c[16*i+14] << 16) | ((unsigned)c[16*i+15] << 24);
    dst[i] = w4;
  }
  wsc[tid] = scale;
  lws[tid] = (float)log2((double)scale);
}

// ---------------- main: 16n x 16o tile, 4-way K-split, 1024 threads (16 waves/CU)
__global__ __launch_bounds__(1024, 4)
void msd_main_kernel(const unsigned short* __restrict__ xp,
                     const unsigned char* __restrict__ wq,
                     const float* __restrict__ xs, const float* __restrict__ lxs,
                     const float* __restrict__ wsc, const float* __restrict__ lws,
                     const float* __restrict__ bias, float* __restrict__ out) {
  __shared__ unsigned short sx[16][1032];   // row stride 2064B -> banks 4*tn apart
  __shared__ unsigned char  swq[16][1040];  // 2-way conflict only (free)
  __shared__ float sxs[16][33], slx[16][33], sws[16][33], slw[16][33];
  __shared__ float sred[3 * 256];
  const int tid = threadIdx.x;
  const int n0 = blockIdx.x * 16, o0 = blockIdx.y * 16;

  // stage x tile: 16 rows x 1024 packed ushorts
  for (int i = tid; i < 16 * 128; i += 1024) {
    int r = i >> 7, c = i & 127;
    uint4 d = ((const uint4*)(xp + (size_t)(n0 + r) * KDIM))[c];
    *(uint4*)&sx[r][c * 8] = d;
  }
  // stage w tile: 16 rows x 1024 bytes
  for (int i = tid; i < 16 * 64; i += 1024) {
    int r = i >> 6, c = i & 63;
    uint4 d = ((const uint4*)(wq + (size_t)(o0 + r) * KDIM))[c];
    *(uint4*)&swq[r][c * 16] = d;
  }
  if (tid < 512) {
    int r = tid >> 5, b = tid & 31;
    sxs[r][b] = xs[(n0 + r) * NB + b];
    slx[r][b] = lxs[(n0 + r) * NB + b];
    sws[r][b] = wsc[(o0 + r) * NB + b];
    slw[r][b] = lws[(o0 + r) * NB + b];
  }
  __syncthreads();

  const int kh = tid >> 8, idx = tid & 255, tn = idx >> 4, to = idx & 15;

  // e_max over blocks (combined_e = floor(lx + lw))
  float emf = -1e30f;
#pragma unroll
  for (int b = 0; b < NB; ++b)
    emf = fmaxf(emf, floorf(slx[tn][b] + slw[to][b]));
  const int iemax = (int)emf;
  // s = 32 - dbase = 24 + min(iemax,0) - ice   (dbase = 8+max(emax,0)-emax+ice)
  const int sbase = 24 + (iemax < 0 ? iemax : 0);

  float facc = 0.f;
  const int b0 = kh * 8;
#pragma unroll 1
  for (int bb = 0; bb < 8; ++bb) {
    const int b = b0 + bb;
    const int ice = (int)floorf(slx[tn][b] + slw[to][b]);
    const int s = sbase - ice;
    uint4 xv0 = *(const uint4*)&sx[tn][b * 32 + 0];
    uint4 xv1 = *(const uint4*)&sx[tn][b * 32 + 8];
    uint4 xv2 = *(const uint4*)&sx[tn][b * 32 + 16];
    uint4 xv3 = *(const uint4*)&sx[tn][b * 32 + 24];
    unsigned xd[16] = {xv0.x, xv0.y, xv0.z, xv0.w, xv1.x, xv1.y, xv1.z, xv1.w,
                       xv2.x, xv2.y, xv2.z, xv2.w, xv3.x, xv3.y, xv3.z, xv3.w};
    uint4 wv0 = *(const uint4*)&swq[to][b * 32];
    uint4 wv1 = *(const uint4*)&swq[to][b * 32 + 16];
    unsigned wb[8] = {wv0.x, wv0.y, wv0.z, wv0.w, wv1.x, wv1.y, wv1.z, wv1.w};
    int bacc = 0;
#pragma unroll
    for (int j = 0; j < 16; ++j) {        // 2 elements per x-dword
      const unsigned xw = xd[j];
      const unsigned ww = wb[j >> 1];
      const int ix0 = ((int)(xw << 24)) >> 24;          // bfe_i32
      const int in0 = (int)((xw >> 8) & 0xFFu);         // bfe_u32
      const int ix1 = ((int)(xw << 8)) >> 24;
      const int in1 = (int)(xw >> 24);
      int iw0, iw1;
      if (j & 1) { iw0 = ((int)(ww << 8)) >> 24; iw1 = ((int)ww) >> 24; }
      else       { iw0 = ((int)(ww << 24)) >> 24; iw1 = ((int)(ww << 16)) >> 24; }
      bacc += naf_keep(ix0 * iw0, in0 + s);
      bacc += naf_keep(ix1 * iw1, in1 + s);
    }
    facc += sxs[tn][b] * sws[to][b] * (float)bacc;  // exact: block_dot = bacc/4096
  }

  if (kh) sred[(kh - 1) * 256 + idx] = facc;
  __syncthreads();
  if (!kh) {
    float r = (facc + sred[idx] + sred[256 + idx] + sred[512 + idx])
              * (1.0f / 4096.0f) + bias[o0 + to];
    out[(size_t)(n0 + tn) * ODIM + (o0 + to)] = r;
  }
}

extern "C" void kernel_launch(void* const* d_in, const int* in_sizes, int n_in,
                              void* d_out, int out_size, void* d_ws, size_t ws_size,
                              hipStream_t stream) {
  const float* x    = (const float*)d_in[0];
  const float* wgt  = (const float*)d_in[1];
  const float* bias = (const float*)d_in[2];
  float* out = (float*)d_out;
  char* ws = (char*)d_ws;
  // workspace layout (16B-aligned)
  unsigned short* xp  = (unsigned short*)(ws + 0);       // 128*1024*2 = 262144
  unsigned char*  wq  = (unsigned char*)(ws + 262144);   // 512*1024   = 524288
  float* xs  = (float*)(ws + 786432);                    // 128*32*4   = 16384
  float* lxs = (float*)(ws + 802816);                    // 16384
  float* wsc = (float*)(ws + 819200);                    // 512*32*4   = 65536
  float* lws = (float*)(ws + 884736);                    // 65536 -> total 950272

  hipLaunchKernelGGL(prep_x_kernel, dim3(16), dim3(256), 0, stream, x, xp, xs, lxs);
  hipLaunchKernelGGL(prep_w_kernel, dim3(64), dim3(256), 0, stream, wgt, wq, wsc, lws);
  hipLaunchKernelGGL(msd_main_kernel, dim3(8, 32), dim3(1024), 0, stream,
                     xp, wq, xs, lxs, wsc, lws, bias, out);
}